// Round 1
// baseline (89945.300 us; speedup 1.0000x reference)
//
#include <hip/hip_runtime.h>

typedef _Float16 f16;
typedef _Float16 half8 __attribute__((ext_vector_type(8)));
typedef float floatx4 __attribute__((ext_vector_type(4)));

#define HD 1024
#define HSZ (128*1024)   // elements of one [128][1024] state buffer

// ---------- math helpers ----------
__device__ __forceinline__ float sigf(float v){ return 1.0f/(1.0f + __expf(-v)); }
__device__ __forceinline__ float tanh_fast(float v){
  float a = fabsf(v);
  float e = __expf(-2.0f*a);
  float t = (1.0f - e)/(1.0f + e);
  return v < 0.0f ? -t : t;
}

// GEMM inner loop: one wave computes a [16 x 16] tile per gate (4 gates).
// A row-major [M][rstride] fp16 (lane m = lane&15, k = quad*8+j)
// B row-major [4096][K] fp16, row = gate*1024 + ncol  (lane n = lane&15)
// Ap/Bp are already offset by (row * stride + q*8 [+ k0]).
__device__ __forceinline__ void gemm4(floatx4* acc, const f16* Ap, const f16* Bp,
                                      size_t gst, int steps){
  for (int kk = 0; kk < steps; ++kk) {
    half8 a = *(const half8*)(Ap + (size_t)kk*32);
    #pragma unroll
    for (int g = 0; g < 4; ++g) {
      half8 b = *(const half8*)(Bp + (size_t)g*gst + (size_t)kk*32);
      acc[g] = __builtin_amdgcn_mfma_f32_16x16x32_f16(a, b, acc[g], 0, 0, 0);
    }
  }
}

// ---------- prep kernels ----------
// out[r][k] = fp16( k < k1 ? A1[r][k] : A2[r][k-k1] ), K = k1+k2
__global__ void cvt_cat(const float* __restrict__ A1, int k1,
                        const float* __restrict__ A2, int k2,
                        f16* __restrict__ outp, long total)
{
  long idx = (long)blockIdx.x*blockDim.x + threadIdx.x;
  if (idx >= total) return;
  int K = k1 + k2;
  long r = idx / K; int k = (int)(idx - r*K);
  float v = (k < k1) ? A1[r*(long)k1 + k] : A2[r*(long)k2 + (k - k1)];
  outp[idx] = (f16)v;
}

__global__ void addvec(const float* __restrict__ a, const float* __restrict__ b,
                       float* __restrict__ o, int nel){
  int i = blockIdx.x*blockDim.x + threadIdx.x;
  if (i < nel) o[i] = a[i] + b[i];
}

__global__ void cvtf16(const float* __restrict__ a, f16* __restrict__ o, long nel){
  long i = (long)blockIdx.x*blockDim.x + threadIdx.x;
  if (i < nel) o[i] = (f16)a[i];
}

__global__ void zero_hc(f16* __restrict__ hb, float* __restrict__ cb){
  long i = (long)blockIdx.x*blockDim.x + threadIdx.x;
  if (i < 3L*2*HSZ) hb[i] = (f16)0.f;
  if (i < 3L*HSZ)   cb[i] = 0.f;
}

// ---------- encoder wavefront stage ----------
// grid 192 x 512. WG = (layer = wg>>6, jb = wg&63). Stage s: layer l works on t = s - l.
// Layer 0: A = [h0(t-1) | x_t]  (K = 1024+32), B0 = [Whh0 | Wih0]
// Layer l>0: A = [h_{l-1}(t) | h_l(t-1)] (K=2048), B = [Wih_l | Whh_l]
// h double-buffered by t-parity: hbuf[layer][parity][128][1024]
__global__ __launch_bounds__(512) void enc_stage(
    int s,
    const f16* __restrict__ B0, const f16* __restrict__ B1, const f16* __restrict__ B2,
    const float* __restrict__ biases, const f16* __restrict__ x16,
    f16* __restrict__ hbuf, float* __restrict__ cbuf)
{
  int wg = blockIdx.x;
  int layer = wg >> 6;
  int jb = wg & 63;
  int t = s - layer;
  if (t < 0 || t >= 512) return;
  int p = t & 1;
  int tid = threadIdx.x;
  int wid = tid >> 6, lane = tid & 63;
  int n = lane & 15, q = lane >> 4;

  const f16* A1; const f16* A2; long rs2; int ks2; const f16* B; int K;
  if (layer == 0) {
    A1 = hbuf + (size_t)(0*2 + (1-p))*HSZ;
    A2 = x16 + (size_t)t*32; rs2 = 512*32; ks2 = 1;
    B = B0; K = 1056;
  } else if (layer == 1) {
    A1 = hbuf + (size_t)(0*2 + p)*HSZ;
    A2 = hbuf + (size_t)(1*2 + (1-p))*HSZ; rs2 = 1024; ks2 = 32;
    B = B1; K = 2048;
  } else {
    A1 = hbuf + (size_t)(1*2 + p)*HSZ;
    A2 = hbuf + (size_t)(2*2 + (1-p))*HSZ; rs2 = 1024; ks2 = 32;
    B = B2; K = 2048;
  }
  f16* hout = hbuf + (size_t)(layer*2 + p)*HSZ;
  float* cl = cbuf + (size_t)layer*HSZ;

  int mrow = wid*16 + n;        // A row this lane loads (wave wid owns M-tile wid)
  int ncol = jb*16 + n;         // hidden index j this lane's column
  size_t gst = (size_t)HD * K;  // B gate stride
  floatx4 acc[4] = {};

  gemm4(acc, A1 + (size_t)mrow*HD + q*8, B + (size_t)ncol*K + q*8, gst, 32);
  gemm4(acc, A2 + (size_t)mrow*rs2 + q*8, B + (size_t)ncol*K + 1024 + q*8, gst, ks2);

  const float* bl = biases + layer*4096;
  float bi = bl[ncol], bf = bl[HD+ncol], bg = bl[2*HD+ncol], bo = bl[3*HD+ncol];
  #pragma unroll
  for (int r = 0; r < 4; ++r) {
    int m = wid*16 + q*4 + r;   // C/D layout: row = quad*4 + reg, col = lane&15
    float iv = sigf(acc[0][r] + bi);
    float fv = sigf(acc[1][r] + bf);
    float gv = tanh_fast(acc[2][r] + bg);
    float ov = sigf(acc[3][r] + bo);
    size_t ci = (size_t)m*HD + ncol;
    float cn = fv*cl[ci] + iv*gv;
    cl[ci] = cn;
    hout[ci] = (f16)(ov * tanh_fast(cn));
  }
}

// ---------- decoder layer-0 stage ----------
// grid 128 x 512. WG = (jb = wg>>1, mh = wg&1) -> 64 batches x 16 j x 4 gates.
// Waves: mtile = wid&3 (16 rows), kh = wid>>2 splits K; LDS combine.
// Also: reduce Wu-partials from previous step's layer-2 into x (teacher forcing select),
// write d_out column t.
__global__ __launch_bounds__(512) void dec_l0(
    int t,
    const f16* __restrict__ Bw, const float* __restrict__ biases,
    const float* __restrict__ w0col, const float* __restrict__ y,
    const int* __restrict__ force, const float* __restrict__ bu_p,
    const float* __restrict__ partial,
    f16* __restrict__ hbuf, float* __restrict__ cbuf, float* __restrict__ dout)
{
  int wg = blockIdx.x;
  int jb = wg >> 1, mh = wg & 1;
  int p = t & 1;
  int tid = threadIdx.x;
  int wid = tid >> 6, lane = tid & 63;
  int mtile = wid & 3, kh = wid >> 2;
  int n = lane & 15, q = lane >> 4;

  __shared__ float xs[64];
  __shared__ floatx4 accsh[4][4][64];

  if (tid < 64) {
    int b = mh*64 + tid;
    float xv;
    if (t == 0) {
      xv = y[(size_t)b*512];
      if (jb == 0) dout[(size_t)b*512] = 0.0f;
    } else {
      float sv = bu_p[0];
      for (int j2 = 0; j2 < 64; ++j2) sv += partial[j2*128 + b];
      if (jb == 0) dout[(size_t)b*512 + t] = sv;       // out(t-1) -> output[:, t]
      xv = (force[t-1] > 0) ? y[(size_t)b*512 + t] : sv;
    }
    xs[tid] = xv;
  }

  int mrow = mh*64 + mtile*16 + n;
  int ncol = jb*16 + n;
  floatx4 acc[4] = {};
  gemm4(acc,
        hbuf + (size_t)(0*2 + (1-p))*HSZ + (size_t)mrow*HD + kh*512 + q*8,
        Bw + (size_t)ncol*HD + kh*512 + q*8,
        (size_t)HD*HD, 16);

  if (kh == 1) {
    #pragma unroll
    for (int g = 0; g < 4; ++g) accsh[mtile][g][lane] = acc[g];
  }
  __syncthreads();
  if (kh == 0) {
    #pragma unroll
    for (int g = 0; g < 4; ++g) acc[g] += accsh[mtile][g][lane];

    const float* bl = biases + 3*4096;
    float bi = bl[ncol], bf = bl[HD+ncol], bg = bl[2*HD+ncol], bo = bl[3*HD+ncol];
    float wi = w0col[ncol], wf = w0col[HD+ncol], wgv = w0col[2*HD+ncol], wo = w0col[3*HD+ncol];
    f16* hout = hbuf + (size_t)(0*2 + p)*HSZ;
    #pragma unroll
    for (int r = 0; r < 4; ++r) {
      int ml = mtile*16 + q*4 + r;
      int m  = mh*64 + ml;
      float xv = xs[ml];
      float iv = sigf(acc[0][r] + bi + xv*wi);
      float fv = sigf(acc[1][r] + bf + xv*wf);
      float gv = tanh_fast(acc[2][r] + bg + xv*wgv);
      float ov = sigf(acc[3][r] + bo + xv*wo);
      size_t ci = (size_t)m*HD + ncol;
      float cn = fv*cbuf[ci] + iv*gv;
      cbuf[ci] = cn;
      hout[ci] = (f16)(ov * tanh_fast(cn));
    }
  }
}

// ---------- decoder layer-1/2 stage ----------
// A = [h_{l-1}(t) | h_l(t-1)] (K=2048) split across kh wave-halves.
// layer==2 additionally computes Wu partial dot-products (shfl-reduced over the 16 j's).
__global__ __launch_bounds__(512) void dec_l12(
    int t, int layer,
    const f16* __restrict__ Bw, const float* __restrict__ biases,
    const float* __restrict__ Wu, float* __restrict__ partial,
    f16* __restrict__ hbuf, float* __restrict__ cbuf)
{
  int wg = blockIdx.x;
  int jb = wg >> 1, mh = wg & 1;
  int p = t & 1;
  int tid = threadIdx.x;
  int wid = tid >> 6, lane = tid & 63;
  int mtile = wid & 3, kh = wid >> 2;
  int n = lane & 15, q = lane >> 4;

  __shared__ floatx4 accsh[4][4][64];

  int mrow = mh*64 + mtile*16 + n;
  int ncol = jb*16 + n;
  const f16* Apiece = kh ? (hbuf + (size_t)(layer*2 + (1-p))*HSZ)
                         : (hbuf + (size_t)((layer-1)*2 + p)*HSZ);
  floatx4 acc[4] = {};
  gemm4(acc,
        Apiece + (size_t)mrow*HD + q*8,
        Bw + (size_t)ncol*2048 + kh*1024 + q*8,
        (size_t)HD*2048, 32);

  if (kh == 1) {
    #pragma unroll
    for (int g = 0; g < 4; ++g) accsh[mtile][g][lane] = acc[g];
  }
  __syncthreads();
  if (kh == 0) {
    #pragma unroll
    for (int g = 0; g < 4; ++g) acc[g] += accsh[mtile][g][lane];

    const float* bl = biases + (size_t)(3+layer)*4096;
    float bi = bl[ncol], bf = bl[HD+ncol], bg = bl[2*HD+ncol], bo = bl[3*HD+ncol];
    float* cl = cbuf + (size_t)layer*HSZ;
    f16* hout = hbuf + (size_t)(layer*2 + p)*HSZ;
    float hnv[4];
    #pragma unroll
    for (int r = 0; r < 4; ++r) {
      int m = mh*64 + mtile*16 + q*4 + r;
      float iv = sigf(acc[0][r] + bi);
      float fv = sigf(acc[1][r] + bf);
      float gv = tanh_fast(acc[2][r] + bg);
      float ov = sigf(acc[3][r] + bo);
      size_t ci = (size_t)m*HD + ncol;
      float cn = fv*cl[ci] + iv*gv;
      cl[ci] = cn;
      float hn = ov * tanh_fast(cn);
      hnv[r] = hn;
      hout[ci] = (f16)hn;
    }
    if (layer == 2) {
      float wj = Wu[ncol];
      float pr[4];
      #pragma unroll
      for (int r = 0; r < 4; ++r) {
        float v = hnv[r]*wj;
        v += __shfl_xor(v, 1); v += __shfl_xor(v, 2);
        v += __shfl_xor(v, 4); v += __shfl_xor(v, 8);
        pr[r] = v;
      }
      if (n == 0) {
        float4 st = make_float4(pr[0], pr[1], pr[2], pr[3]);
        *(float4*)(partial + jb*128 + mh*64 + mtile*16 + q*4) = st;
      }
    }
  }
}

// final out(510) -> output[:, 511]
__global__ void dec_epi(const float* __restrict__ partial, const float* __restrict__ bu_p,
                        float* __restrict__ dout)
{
  int b = threadIdx.x;  // 128
  float sv = bu_p[0];
  for (int j2 = 0; j2 < 64; ++j2) sv += partial[j2*128 + b];
  dout[(size_t)b*512 + 511] = sv;
}

// ---------- host ----------
extern "C" void kernel_launch(void* const* d_in, const int* in_sizes, int n_in,
                              void* d_out, int out_size, void* d_ws, size_t ws_size,
                              hipStream_t stream)
{
  const float* x     = (const float*)d_in[0];
  const float* y     = (const float*)d_in[1];
  const int*   force = (const int*)  d_in[2];
  const float* eWih0 = (const float*)d_in[3];
  const float* eWhh0 = (const float*)d_in[4];
  const float* ebih0 = (const float*)d_in[5];
  const float* ebhh0 = (const float*)d_in[6];
  const float* eWih  = (const float*)d_in[7];
  const float* eWhh  = (const float*)d_in[8];
  const float* ebih  = (const float*)d_in[9];
  const float* ebhh  = (const float*)d_in[10];
  const float* dWih0 = (const float*)d_in[11];
  const float* dWhh0 = (const float*)d_in[12];
  const float* dbih0 = (const float*)d_in[13];
  const float* dbhh0 = (const float*)d_in[14];
  const float* dWih  = (const float*)d_in[15];
  const float* dWhh  = (const float*)d_in[16];
  const float* dbih  = (const float*)d_in[17];
  const float* dbhh  = (const float*)d_in[18];
  const float* Wu    = (const float*)d_in[19];
  const float* bu    = (const float*)d_in[20];
  float* out = (float*)d_out;

  char* ws = (char*)d_ws;
  size_t off = 0;
  auto alloc = [&](size_t bytes)->void* {
    void* pp = ws + off; off += (bytes + 255) & ~(size_t)255; return pp;
  };
  f16* B_e0 = (f16*)alloc(4096ULL*1056*2);
  f16* B_e1 = (f16*)alloc(4096ULL*2048*2);
  f16* B_e2 = (f16*)alloc(4096ULL*2048*2);
  f16* B_d0 = (f16*)alloc(4096ULL*1024*2);
  f16* B_d1 = (f16*)alloc(4096ULL*2048*2);
  f16* B_d2 = (f16*)alloc(4096ULL*2048*2);
  float* biases = (float*)alloc(6ULL*4096*4);
  f16* x16  = (f16*)alloc(128ULL*512*32*2);
  f16* hbuf = (f16*)alloc(3ULL*2*HSZ*2);
  float* cbuf = (float*)alloc(3ULL*HSZ*4);
  float* partial = (float*)alloc(64ULL*128*4);
  (void)ws_size; (void)in_sizes; (void)n_in; (void)out_size;

  const int THR = 256;
  auto blocks = [&](long nel){ return dim3((unsigned)((nel + THR - 1)/THR)); };

  // --- prep ---
  hipLaunchKernelGGL(cvt_cat, blocks(4096L*1056), dim3(THR), 0, stream,
                     eWhh0, 1024, eWih0, 32, B_e0, 4096L*1056);
  hipLaunchKernelGGL(cvt_cat, blocks(4096L*2048), dim3(THR), 0, stream,
                     eWih, 1024, eWhh, 1024, B_e1, 4096L*2048);
  hipLaunchKernelGGL(cvt_cat, blocks(4096L*2048), dim3(THR), 0, stream,
                     eWih + 4096L*1024, 1024, eWhh + 4096L*1024, 1024, B_e2, 4096L*2048);
  hipLaunchKernelGGL(cvt_cat, blocks(4096L*1024), dim3(THR), 0, stream,
                     dWhh0, 1024, dWhh0, 0, B_d0, 4096L*1024);
  hipLaunchKernelGGL(cvt_cat, blocks(4096L*2048), dim3(THR), 0, stream,
                     dWih, 1024, dWhh, 1024, B_d1, 4096L*2048);
  hipLaunchKernelGGL(cvt_cat, blocks(4096L*2048), dim3(THR), 0, stream,
                     dWih + 4096L*1024, 1024, dWhh + 4096L*1024, 1024, B_d2, 4096L*2048);

  hipLaunchKernelGGL(addvec, blocks(4096), dim3(THR), 0, stream, ebih0, ebhh0, biases + 0*4096, 4096);
  hipLaunchKernelGGL(addvec, blocks(4096), dim3(THR), 0, stream, ebih, ebhh, biases + 1*4096, 4096);
  hipLaunchKernelGGL(addvec, blocks(4096), dim3(THR), 0, stream, ebih + 4096, ebhh + 4096, biases + 2*4096, 4096);
  hipLaunchKernelGGL(addvec, blocks(4096), dim3(THR), 0, stream, dbih0, dbhh0, biases + 3*4096, 4096);
  hipLaunchKernelGGL(addvec, blocks(4096), dim3(THR), 0, stream, dbih, dbhh, biases + 4*4096, 4096);
  hipLaunchKernelGGL(addvec, blocks(4096), dim3(THR), 0, stream, dbih + 4096, dbhh + 4096, biases + 5*4096, 4096);

  hipLaunchKernelGGL(cvtf16, blocks(128L*512*32), dim3(THR), 0, stream, x, x16, 128L*512*32);
  hipLaunchKernelGGL(zero_hc, blocks(3L*2*HSZ), dim3(THR), 0, stream, hbuf, cbuf);

  // --- encoder: wavefront over (layer, t) ---
  for (int s = 0; s < 514; ++s)
    hipLaunchKernelGGL(enc_stage, dim3(192), dim3(512), 0, stream,
                       s, B_e0, B_e1, B_e2, biases, x16, hbuf, cbuf);

  // --- decoder: 511 steps x 3 layer-stages ---
  for (int t = 0; t < 511; ++t) {
    hipLaunchKernelGGL(dec_l0, dim3(128), dim3(512), 0, stream,
                       t, B_d0, biases, dWih0, y, force, bu, partial, hbuf, cbuf, out);
    hipLaunchKernelGGL(dec_l12, dim3(128), dim3(512), 0, stream,
                       t, 1, B_d1, biases, Wu, partial, hbuf, cbuf);
    hipLaunchKernelGGL(dec_l12, dim3(128), dim3(512), 0, stream,
                       t, 2, B_d2, biases, Wu, partial, hbuf, cbuf);
  }
  hipLaunchKernelGGL(dec_epi, dim3(1), dim3(128), 0, stream, partial, bu, out);
}